// Round 1
// baseline (141.016 us; speedup 1.0000x reference)
//
#include <hip/hip_runtime.h>

#define IN_N   4096
#define OW     4084          // (4096 + 2*1 - 15) + 1
#define KS     15
#define TILE   64            // 64x64 output tile per block (4 waves x 16 rows)
#define XROWS  78            // TILE + KS - 1
#define XS     88            // LDS row stride in halfwords (176 B = 16B-multiple)
#define NBX    64
#define NBY    64

typedef __attribute__((ext_vector_type(8))) short     v8s;   // raw 16B
typedef __attribute__((ext_vector_type(8))) _Float16  v8h;   // f16 A/B frag (4 VGPR)
typedef __attribute__((ext_vector_type(2))) _Float16  v2h;
typedef __attribute__((ext_vector_type(4))) float     v4f;   // C/D frag
typedef __attribute__((ext_vector_type(2))) float     v2f;
typedef __attribute__((ext_vector_type(2))) unsigned  v2u;

// ---- pre-kernel: build the 15 banded-B MFMA fragments once into d_ws ----
// Band shifted by +1 vs previous version: B_ky[k][n] = w[ky, k-1-n] (k in [1,31))
// so the A k-window starts at EVEN global col X0-2 -> aligned float2 staging.
// lane e holds B[k = (e>>4)*8 + j][n = e&15], j = 0..7  (16 B per lane)
__global__ void build_B(const float* __restrict__ w, unsigned short* __restrict__ Bg) {
    int ky = blockIdx.x;         // 15
    int e  = threadIdx.x;        // 64
    int n = e & 15, quad = e >> 4;
    unsigned short vals[8];
    #pragma unroll
    for (int j = 0; j < 8; ++j) {
        int d = quad * 8 + j - 1 - n;                 // shifted band
        _Float16 h = (_Float16)0.0f;
        if (d >= 0 && d < KS) h = (_Float16)w[ky * KS + d];   // RTNE f32->f16
        union { _Float16 hh; unsigned short u; } cv; cv.hh = h;
        vals[j] = cv.u;
    }
    *(v8s*)(&Bg[(ky * 64 + e) * 8]) = *(const v8s*)vals;
}

__global__ __launch_bounds__(256, 8) void conv2d_mfma3(
    const float* __restrict__ x, const unsigned short* __restrict__ Bg,
    const float* __restrict__ bias, float* __restrict__ out)
{
    __shared__ unsigned short xtile[XROWS * XS] __attribute__((aligned(16)));

    const int tid = threadIdx.x;
    const int bx = blockIdx.x, by = blockIdx.y;
    const int X0 = bx * TILE;
    const int Y0 = by * TILE;
    const bool interior = (bx > 0) & (bx < NBX - 1) & (by > 0) & (by < NBY - 1);

    // ---- stage input tile fp32 -> f16 ----
    // LDS (row, col) = global (Y0-1+row, X0-2+col), col in [0,80)
    // 240 threads as 12 rows x 20 four-col units; 7 row-sweeps cover 78 rows.
    if (tid < 240) {
        const int tcol = tid % 20;
        const int trow = tid / 20;                    // 0..11
        const int c0 = 4 * tcol;                      // LDS halfword col, 8B-aligned
        unsigned short* dst = &xtile[trow * XS + c0];
        if (interior) {
            const float* xr = x + (size_t)(Y0 - 1 + trow) * IN_N + (X0 - 2 + c0);
            #pragma unroll
            for (int i = 0; i < 7; ++i) {
                if (i < 6 || trow < 6) {              // rows 72..77 on last sweep
                    v2f f01 = *(const v2f*)xr;        // aligned dwordx2 (even col)
                    v2f f23 = *(const v2f*)(xr + 2);
                    v2u p;
                    p.x = __builtin_bit_cast(unsigned, __builtin_amdgcn_cvt_pkrtz(f01.x, f01.y));
                    p.y = __builtin_bit_cast(unsigned, __builtin_amdgcn_cvt_pkrtz(f23.x, f23.y));
                    *(v2u*)dst = p;                   // ds_write_b64
                }
                xr  += 12 * (size_t)IN_N;
                dst += 12 * XS;
            }
        } else {
            const int gc0 = X0 - 2 + c0;
            #pragma unroll
            for (int i = 0; i < 7; ++i) {
                int row = trow + 12 * i;
                if (row < XROWS) {
                    int gr = Y0 - 1 + row;
                    float f0 = 0.f, f1 = 0.f, f2 = 0.f, f3 = 0.f;
                    if ((unsigned)gr < (unsigned)IN_N) {
                        const float* xr = x + (size_t)gr * IN_N;
                        if ((unsigned)(gc0 + 0) < (unsigned)IN_N) f0 = xr[gc0 + 0];
                        if ((unsigned)(gc0 + 1) < (unsigned)IN_N) f1 = xr[gc0 + 1];
                        if ((unsigned)(gc0 + 2) < (unsigned)IN_N) f2 = xr[gc0 + 2];
                        if ((unsigned)(gc0 + 3) < (unsigned)IN_N) f3 = xr[gc0 + 3];
                    }
                    v2u p;
                    p.x = __builtin_bit_cast(unsigned, __builtin_amdgcn_cvt_pkrtz(f0, f1));
                    p.y = __builtin_bit_cast(unsigned, __builtin_amdgcn_cvt_pkrtz(f2, f3));
                    *(v2u*)(&xtile[row * XS + c0]) = p;
                }
            }
        }
    }
    __syncthreads();

    // ---- MFMA main loop ----
    const int lane = tid & 63;
    const int wv   = tid >> 6;
    const int m    = lane & 15;
    const int quad = lane >> 4;

    v4f acc[4];
    #pragma unroll
    for (int t = 0; t < 4; ++t) acc[t] = (v4f){0.f, 0.f, 0.f, 0.f};

    const v8h* Bgv = (const v8h*)Bg;
    v8h bcur = Bgv[lane];                             // ky = 0 (L2-resident)
    const unsigned short* arow = &xtile[(wv * 16 + m) * XS + quad * 8];

    #pragma unroll
    for (int ky = 0; ky < KS; ++ky) {
        v8h bnext = (ky < KS - 1) ? Bgv[(ky + 1) * 64 + lane] : bcur;
        v8h a0 = *(const v8h*)(arow + 0);             // 16B-aligned ds_read_b128
        v8h a1 = *(const v8h*)(arow + 16);
        v8h a2 = *(const v8h*)(arow + 32);
        v8h a3 = *(const v8h*)(arow + 48);
        acc[0] = __builtin_amdgcn_mfma_f32_16x16x32_f16(a0, bcur, acc[0], 0, 0, 0);
        acc[1] = __builtin_amdgcn_mfma_f32_16x16x32_f16(a1, bcur, acc[1], 0, 0, 0);
        acc[2] = __builtin_amdgcn_mfma_f32_16x16x32_f16(a2, bcur, acc[2], 0, 0, 0);
        acc[3] = __builtin_amdgcn_mfma_f32_16x16x32_f16(a3, bcur, acc[3], 0, 0, 0);
        arow += XS;
        bcur = bnext;
    }

    // ---- epilogue: D[m,n] -> out; row = quad*4 + r, col = lane&15 (+t*16) ----
    const float bv = bias[0];
    const int orow0 = Y0 + wv * 16 + quad * 4;
    const int ocol0 = X0 + m;
    if (interior | ((bx < NBX - 1) & (by < NBY - 1))) {
        float* o0 = &out[(size_t)orow0 * OW + ocol0];
        #pragma unroll
        for (int t = 0; t < 4; ++t) {
            #pragma unroll
            for (int r = 0; r < 4; ++r)
                o0[(size_t)r * OW + t * 16] = acc[t][r] + bv;
        }
    } else {
        #pragma unroll
        for (int t = 0; t < 4; ++t) {
            int oc = ocol0 + t * 16;
            if (oc < OW) {
                #pragma unroll
                for (int r = 0; r < 4; ++r) {
                    int orow = orow0 + r;
                    if (orow < OW)
                        out[(size_t)orow * OW + oc] = acc[t][r] + bv;
                }
            }
        }
    }
}

extern "C" void kernel_launch(void* const* d_in, const int* in_sizes, int n_in,
                              void* d_out, int out_size, void* d_ws, size_t ws_size,
                              hipStream_t stream) {
    const float* x    = (const float*)d_in[0];
    const float* w    = (const float*)d_in[1];
    const float* bias = (const float*)d_in[2];
    float* out        = (float*)d_out;
    unsigned short* Bg = (unsigned short*)d_ws;     // 15 KiB of scratch

    build_B<<<dim3(KS), dim3(64), 0, stream>>>(w, Bg);
    dim3 grid(NBX, NBY);
    conv2d_mfma3<<<grid, dim3(256), 0, stream>>>(x, Bg, bias, out);
}